// Round 1
// baseline (208.530 us; speedup 1.0000x reference)
//
#include <hip/hip_runtime.h>
#include <math.h>

// ---------- types ----------
typedef __attribute__((ext_vector_type(8))) short bf16x8;   // 8 x bf16 (lax vector conv to builtin type)
typedef __attribute__((ext_vector_type(4))) float f32x4;

#define AS1(p) ((__attribute__((address_space(1))) void*)(uintptr_t)(p))
#define AS3(p) ((__attribute__((address_space(3))) void*)(p))

static __device__ __forceinline__ unsigned short f2bf(float f) {
    unsigned int u = __float_as_uint(f);
    unsigned int r = (u + 0x7fffu + ((u >> 16) & 1u)) >> 16;   // RNE
    return (unsigned short)r;
}

// ---------- sizes ----------
#define NPATCH 8191
#define NTOK   8192          // with cls row 0
#define INDIM  1024
#define EMBED  512

// ============================================================
// 1) x (8191x1024 f32) -> xb (8192x1024 bf16), last row zeroed
// ============================================================
__global__ void k_convert_x(const float* __restrict__ x, unsigned short* __restrict__ xb) {
    const int NV = NPATCH * INDIM / 4;   // 2,096,896 valid float4s
    const int NT = NTOK   * INDIM / 4;   // 2,097,152 total
    for (int i = blockIdx.x * blockDim.x + threadIdx.x; i < NT; i += gridDim.x * blockDim.x) {
        ushort4 o;
        if (i < NV) {
            float4 v = ((const float4*)x)[i];
            o.x = f2bf(v.x); o.y = f2bf(v.y); o.z = f2bf(v.z); o.w = f2bf(v.w);
        } else {
            o.x = 0; o.y = 0; o.z = 0; o.w = 0;
        }
        ((ushort4*)xb)[i] = o;
    }
}

// ============================================================
// 2) W1 (1024x512 f32, [K][N]) -> w1t (512x1024 bf16, [N][K])
// ============================================================
__global__ void k_transpose_w1(const float* __restrict__ W1, unsigned short* __restrict__ w1t) {
    __shared__ float tile[32][33];
    const int bk = blockIdx.x >> 4;          // 0..31 (K tiles)
    const int bn = blockIdx.x & 15;          // 0..15 (N tiles)
    const int t  = threadIdx.x;
    const int r  = t >> 3;                   // 0..31
    const int c4 = (t & 7) * 4;              // 0,4,..,28
    float4 v = *(const float4*)(W1 + (size_t)(bk * 32 + r) * EMBED + bn * 32 + c4);
    tile[r][c4 + 0] = v.x; tile[r][c4 + 1] = v.y; tile[r][c4 + 2] = v.z; tile[r][c4 + 3] = v.w;
    __syncthreads();
    // out element (n, k) = W1[k][n] = tile[k - bk*32][n - bn*32]
    ushort4 o;
    o.x = f2bf(tile[c4 + 0][r]); o.y = f2bf(tile[c4 + 1][r]);
    o.z = f2bf(tile[c4 + 2][r]); o.w = f2bf(tile[c4 + 3][r]);
    *(ushort4*)(w1t + (size_t)(bn * 32 + r) * INDIM + bk * 32 + c4) = o;
}

// ============================================================
// 3) q0 = cls @ Wq + bq ; also h_full row0 = cls ; zero svec
//    grid 4 x 128
// ============================================================
__global__ void k_q0(const float* __restrict__ cls, const float* __restrict__ Wq,
                     const float* __restrict__ bq, float* __restrict__ q0,
                     float* __restrict__ h_full, float* __restrict__ svec) {
    const int d = blockIdx.x * 128 + threadIdx.x;   // 0..511
    float acc = 0.f;
    for (int in = 0; in < EMBED; ++in)
        acc = fmaf(cls[in], Wq[in * EMBED + d], acc);
    q0[d]     = acc + bq[d];
    h_full[d] = cls[d];
    svec[d]   = 0.f;
}

// ============================================================
// 4) u[in] = Wk[in,:] . q0   (so scores = h . u)  grid 32 x 256
// ============================================================
__global__ void k_u(const float* __restrict__ Wk, const float* __restrict__ q0,
                    float* __restrict__ u) {
    const int wave = blockIdx.x * 4 + (threadIdx.x >> 6);  // 0..127
    const int lane = threadIdx.x & 63;
    const float4* q4 = (const float4*)q0;
    float4 qa = q4[lane * 2], qb = q4[lane * 2 + 1];
    for (int rr = 0; rr < 4; ++rr) {
        const int row = wave * 4 + rr;                     // 0..511
        const float4* wr = (const float4*)(Wk + (size_t)row * EMBED);
        float4 a = wr[lane * 2], b = wr[lane * 2 + 1];
        float acc = a.x*qa.x + a.y*qa.y + a.z*qa.z + a.w*qa.w
                  + b.x*qb.x + b.y*qb.y + b.z*qb.z + b.w*qb.w;
        for (int off = 32; off; off >>= 1) acc += __shfl_down(acc, off);
        if (lane == 0) u[row] = acc;
    }
}

// ============================================================
// 5) GEMM: h_full[1+m][n] = relu( xb[m,:] @ w1t[n,:]^T + b1[n] )
//    128x128 tile, BK=32, 4 waves (2x2), mfma 16x16x32 bf16
//    grid 256 (64 M-tiles x 4 N-tiles), block 256
// ============================================================
__global__ __launch_bounds__(256) void k_gemm(const unsigned short* __restrict__ xb,
                                              const unsigned short* __restrict__ w1t,
                                              const float* __restrict__ b1,
                                              float* __restrict__ h_full) {
    __shared__ unsigned short As[128 * 32];   // [row][k], 64B rows
    __shared__ unsigned short Bs[128 * 32];   // [col][k]
    const int tid  = threadIdx.x;
    const int wave = tid >> 6;
    const int lane = tid & 63;
    const int gm   = blockIdx.x >> 2;         // 0..63
    const int gn   = blockIdx.x & 3;          // 0..3
    const int wr   = wave >> 1, wc = wave & 1;

    const int rowInChunk = lane >> 2;         // 0..15
    const int kOff       = (lane & 3) * 8;    // 0,8,16,24

    f32x4 acc[4][4] = {};

    const int fr = lane & 15;
    const int fq = lane >> 4;

    for (int kt = 0; kt < INDIM / 32; ++kt) {
        const int k0 = kt * 32;
        __syncthreads();   // previous compute done before overwrite
        // stage A (8KB) and B (8KB): 2 rounds each, 1KB per wave per round
        #pragma unroll
        for (int r = 0; r < 2; ++r) {
            const int c = r * 4 + wave;                   // chunk 0..7, 16 rows each
            const int arow = gm * 128 + c * 16 + rowInChunk;
            __builtin_amdgcn_global_load_lds(
                AS1(xb + (size_t)arow * INDIM + k0 + kOff),
                AS3(As + c * 512), 16, 0, 0);
            const int brow = gn * 128 + c * 16 + rowInChunk;
            __builtin_amdgcn_global_load_lds(
                AS1(w1t + (size_t)brow * INDIM + k0 + kOff),
                AS3(Bs + c * 512), 16, 0, 0);
        }
        __syncthreads();   // compiler drains vmcnt before barrier

        bf16x8 af[4], bf[4];
        #pragma unroll
        for (int mi = 0; mi < 4; ++mi)
            af[mi] = *(const bf16x8*)&As[(wr * 64 + mi * 16 + fr) * 32 + fq * 8];
        #pragma unroll
        for (int ni = 0; ni < 4; ++ni)
            bf[ni] = *(const bf16x8*)&Bs[(wc * 64 + ni * 16 + fr) * 32 + fq * 8];
        #pragma unroll
        for (int mi = 0; mi < 4; ++mi)
            #pragma unroll
            for (int ni = 0; ni < 4; ++ni)
                acc[mi][ni] = __builtin_amdgcn_mfma_f32_16x16x32_bf16(af[mi], bf[ni], acc[mi][ni], 0, 0, 0);
    }

    // epilogue: D[i][j]: j = lane&15, i = 4*(lane>>4)+r
    #pragma unroll
    for (int mi = 0; mi < 4; ++mi) {
        #pragma unroll
        for (int r = 0; r < 4; ++r) {
            const int m = gm * 128 + wr * 64 + mi * 16 + fq * 4 + r;
            if (m < NPATCH) {
                #pragma unroll
                for (int ni = 0; ni < 4; ++ni) {
                    const int col = gn * 128 + wc * 64 + ni * 16 + fr;
                    float v = acc[mi][ni][r] + b1[col];
                    h_full[(size_t)(m + 1) * EMBED + col] = fmaxf(v, 0.f);
                }
            }
        }
    }
}

// ============================================================
// 6) scores[j] = (h_full[j] . u) / sqrt(512)   grid 2048 x 256
// ============================================================
__global__ void k_scores(const float* __restrict__ h_full, const float* __restrict__ u,
                         float* __restrict__ scores) {
    const int j    = blockIdx.x * 4 + (threadIdx.x >> 6);
    const int lane = threadIdx.x & 63;
    const float4* hr = (const float4*)(h_full + (size_t)j * EMBED);
    const float4* u4 = (const float4*)u;
    float4 a = hr[lane * 2], b = hr[lane * 2 + 1];
    float4 qa = u4[lane * 2], qb = u4[lane * 2 + 1];
    float acc = a.x*qa.x + a.y*qa.y + a.z*qa.z + a.w*qa.w
              + b.x*qb.x + b.y*qb.y + b.z*qb.z + b.w*qb.w;
    for (int off = 32; off; off >>= 1) acc += __shfl_down(acc, off);
    if (lane == 0) scores[j] = acc * 0.04419417382415922f;   // 1/sqrt(512)
}

// ============================================================
// 7) chunk softmax (16 x 512) then full softmax -> wts[8192]
//    1 block x 1024 threads; wave == chunk
// ============================================================
__global__ void k_softmax(const float* __restrict__ scores, float* __restrict__ wts) {
    __shared__ float redA[16], redB[16];
    const int t = threadIdx.x, wv = t >> 6, lane = t & 63;
    const float4* s4 = (const float4*)scores;
    float4 a = s4[2 * t], b = s4[2 * t + 1];
    float v[8] = {a.x, a.y, a.z, a.w, b.x, b.y, b.z, b.w};

    // per-chunk softmax (one wave == one 512-chunk)
    float mx = v[0];
    #pragma unroll
    for (int j = 1; j < 8; ++j) mx = fmaxf(mx, v[j]);
    for (int off = 32; off; off >>= 1) mx = fmaxf(mx, __shfl_xor(mx, off));
    float sm = 0.f;
    #pragma unroll
    for (int j = 0; j < 8; ++j) { v[j] = expf(v[j] - mx); sm += v[j]; }
    for (int off = 32; off; off >>= 1) sm += __shfl_xor(sm, off);
    float inv = 1.f / sm;
    #pragma unroll
    for (int j = 0; j < 8; ++j) v[j] *= inv;

    // full softmax over all 8192
    float m2 = v[0];
    #pragma unroll
    for (int j = 1; j < 8; ++j) m2 = fmaxf(m2, v[j]);
    for (int off = 32; off; off >>= 1) m2 = fmaxf(m2, __shfl_xor(m2, off));
    if (lane == 0) redA[wv] = m2;
    __syncthreads();
    float gm = redA[0];
    for (int i = 1; i < 16; ++i) gm = fmaxf(gm, redA[i]);
    float s2 = 0.f;
    #pragma unroll
    for (int j = 0; j < 8; ++j) { v[j] = expf(v[j] - gm); s2 += v[j]; }
    for (int off = 32; off; off >>= 1) s2 += __shfl_xor(s2, off);
    if (lane == 0) redB[wv] = s2;
    __syncthreads();
    float gs = 0.f;
    for (int i = 0; i < 16; ++i) gs += redB[i];
    float gi = 1.f / gs;
    float4 o1 = {v[0] * gi, v[1] * gi, v[2] * gi, v[3] * gi};
    float4 o2 = {v[4] * gi, v[5] * gi, v[6] * gi, v[7] * gi};
    float4* w4 = (float4*)wts;
    w4[2 * t] = o1; w4[2 * t + 1] = o2;
}

// ============================================================
// 8) svec[d] = sum_j wts[j] * h_full[j][d]   grid 128 x 256
// ============================================================
__global__ void k_wsum(const float* __restrict__ h_full, const float* __restrict__ wts,
                       float* __restrict__ svec) {
    const int b = blockIdx.x, t = threadIdx.x;
    float a0 = 0.f, a1 = 0.f;
    const int j0 = b * 64;
    for (int j = j0; j < j0 + 64; ++j) {
        const float wj = wts[j];
        const float* hr = h_full + (size_t)j * EMBED;
        a0 = fmaf(wj, hr[t], a0);
        a1 = fmaf(wj, hr[t + 256], a1);
    }
    atomicAdd(&svec[t], a0);
    atomicAdd(&svec[t + 256], a1);
}

// ============================================================
// 9) attn0[d] = svec @ Wv + bv        grid 8 x 64
// ============================================================
__global__ void k_attn0(const float* __restrict__ svec, const float* __restrict__ Wv,
                        const float* __restrict__ bv, float* __restrict__ attn0) {
    const int d = blockIdx.x * 64 + threadIdx.x;
    float acc = 0.f;
    for (int e = 0; e < EMBED; ++e)
        acc = fmaf(svec[e], Wv[(size_t)e * EMBED + d], acc);
    attn0[d] = acc + bv[d];
}

// ============================================================
// 10) r0[d] = cls[d] + attn0 @ Wo + bo   grid 8 x 64
// ============================================================
__global__ void k_r0(const float* __restrict__ cls, const float* __restrict__ attn0,
                     const float* __restrict__ Wo, const float* __restrict__ bo,
                     float* __restrict__ r0) {
    const int d = blockIdx.x * 64 + threadIdx.x;
    float acc = 0.f;
    for (int e = 0; e < EMBED; ++e)
        acc = fmaf(attn0[e], Wo[(size_t)e * EMBED + d], acc);
    r0[d] = cls[d] + acc + bo[d];
}

// ============================================================
// 11) LayerNorm(r0) -> logits = hn @ Wc + bc    1 block x 512
// ============================================================
__global__ void k_final(const float* __restrict__ r0, const float* __restrict__ ln_g,
                        const float* __restrict__ ln_b, const float* __restrict__ Wc,
                        const float* __restrict__ bc, float* __restrict__ out) {
    __shared__ float red[8];
    const int t = threadIdx.x, wv = t >> 6, lane = t & 63;
    const float x = r0[t];

    float sm = x;
    for (int off = 32; off; off >>= 1) sm += __shfl_down(sm, off);
    if (lane == 0) red[wv] = sm;
    __syncthreads();
    float mu = 0.f;
    for (int i = 0; i < 8; ++i) mu += red[i];
    mu *= (1.f / 512.f);
    const float dx = x - mu;

    __syncthreads();
    float q = dx * dx;
    for (int off = 32; off; off >>= 1) q += __shfl_down(q, off);
    if (lane == 0) red[wv] = q;
    __syncthreads();
    float var = 0.f;
    for (int i = 0; i < 8; ++i) var += red[i];
    var *= (1.f / 512.f);

    const float hn = dx / sqrtf(var + 1e-5f) * ln_g[t] + ln_b[t];
    float p0 = hn * Wc[2 * t];
    float p1 = hn * Wc[2 * t + 1];

    __syncthreads();
    for (int off = 32; off; off >>= 1) p0 += __shfl_down(p0, off);
    if (lane == 0) red[wv] = p0;
    __syncthreads();
    if (t == 0) {
        float tot = 0.f;
        for (int i = 0; i < 8; ++i) tot += red[i];
        out[0] = tot + bc[0];
    }
    __syncthreads();
    for (int off = 32; off; off >>= 1) p1 += __shfl_down(p1, off);
    if (lane == 0) red[wv] = p1;
    __syncthreads();
    if (t == 0) {
        float tot = 0.f;
        for (int i = 0; i < 8; ++i) tot += red[i];
        out[1] = tot + bc[1];
    }
}

// ============================================================
extern "C" void kernel_launch(void* const* d_in, const int* in_sizes, int n_in,
                              void* d_out, int out_size, void* d_ws, size_t ws_size,
                              hipStream_t stream) {
    const float* x    = (const float*)d_in[0];
    const float* W1   = (const float*)d_in[1];
    const float* b1   = (const float*)d_in[2];
    const float* cls  = (const float*)d_in[3];
    const float* Wq   = (const float*)d_in[4];
    const float* bq   = (const float*)d_in[5];
    const float* Wk   = (const float*)d_in[6];
    const float* bk   = (const float*)d_in[7];   (void)bk;  // uniform shift cancels in softmax
    const float* Wv   = (const float*)d_in[8];
    const float* bv   = (const float*)d_in[9];
    const float* Wo   = (const float*)d_in[10];
    const float* bo   = (const float*)d_in[11];
    const float* ln_g = (const float*)d_in[12];
    const float* ln_b = (const float*)d_in[13];
    const float* Wc   = (const float*)d_in[14];
    const float* bc   = (const float*)d_in[15];
    float* out = (float*)d_out;

    char* ws = (char*)d_ws;
    unsigned short* xb     = (unsigned short*)(ws);                    // 16 MB
    unsigned short* w1t    = (unsigned short*)(ws + 16777216);         // 1 MB
    float*          h_full = (float*)(ws + 17825792);                  // 16 MB
    float*          scores = (float*)(ws + 34603008);                  // 32 KB
    float*          wts    = (float*)(ws + 34635776);                  // 32 KB
    float*          q0     = (float*)(ws + 34668544);
    float*          u      = (float*)(ws + 34670592);
    float*          svec   = (float*)(ws + 34672640);
    float*          attn0  = (float*)(ws + 34674688);
    float*          r0     = (float*)(ws + 34676736);

    k_convert_x  <<<2048, 256, 0, stream>>>(x, xb);
    k_transpose_w1<<<512, 256, 0, stream>>>(W1, w1t);
    k_q0         <<<4,   128, 0, stream>>>(cls, Wq, bq, q0, h_full, svec);
    k_u          <<<32,  256, 0, stream>>>(Wk, q0, u);
    k_gemm       <<<256, 256, 0, stream>>>(xb, w1t, b1, h_full);
    k_scores     <<<2048,256, 0, stream>>>(h_full, u, scores);
    k_softmax    <<<1,  1024, 0, stream>>>(scores, wts);
    k_wsum       <<<128, 256, 0, stream>>>(h_full, wts, svec);
    k_attn0      <<<8,    64, 0, stream>>>(svec, Wv, bv, attn0);
    k_r0         <<<8,    64, 0, stream>>>(cls, attn0, Wo, bo, r0);
    k_final      <<<1,   512, 0, stream>>>(r0, ln_g, ln_b, Wc, bc, out);
}

// Round 3
// 205.669 us; speedup vs baseline: 1.0139x; 1.0139x over previous
//
#include <hip/hip_runtime.h>
#include <math.h>

// ---------- types ----------
typedef __attribute__((ext_vector_type(8))) short bf16x8;   // 8 x bf16
typedef __attribute__((ext_vector_type(4))) float f32x4;

static __device__ __forceinline__ unsigned short f2bf(float f) {
    unsigned int u = __float_as_uint(f);
    unsigned int r = (u + 0x7fffu + ((u >> 16) & 1u)) >> 16;   // RNE
    return (unsigned short)r;
}
static __device__ __forceinline__ unsigned int cvtpk_bf16(float lo, float hi) {
    unsigned int r;
    asm("v_cvt_pk_bf16_f32 %0, %1, %2" : "=v"(r) : "v"(lo), "v"(hi));
    return r;
}

// ---------- sizes ----------
#define NPATCH 8191
#define NTOK   8192          // with cls row 0
#define INDIM  1024
#define EMBED  512

// ============================================================
// 1) W1 (1024x512 f32, [K][N]) -> w1t (512x1024 bf16, [N][K])
// ============================================================
__global__ void k_transpose_w1(const float* __restrict__ W1, unsigned short* __restrict__ w1t) {
    __shared__ float tile[32][33];
    const int bk = blockIdx.x >> 4;          // 0..31 (K tiles)
    const int bn = blockIdx.x & 15;          // 0..15 (N tiles)
    const int t  = threadIdx.x;
    const int r  = t >> 3;                   // 0..31
    const int c4 = (t & 7) * 4;              // 0,4,..,28
    float4 v = *(const float4*)(W1 + (size_t)(bk * 32 + r) * EMBED + bn * 32 + c4);
    tile[r][c4 + 0] = v.x; tile[r][c4 + 1] = v.y; tile[r][c4 + 2] = v.z; tile[r][c4 + 3] = v.w;
    __syncthreads();
    ushort4 o;
    o.x = f2bf(tile[c4 + 0][r]); o.y = f2bf(tile[c4 + 1][r]);
    o.z = f2bf(tile[c4 + 2][r]); o.w = f2bf(tile[c4 + 3][r]);
    *(ushort4*)(w1t + (size_t)(bn * 32 + r) * INDIM + bk * 32 + c4) = o;
}

// ============================================================
// 2) q0 = cls @ Wq + bq ; h_full row0 = cls ; zero svec+scores
//    grid 8 x 64
// ============================================================
__global__ void k_q0(const float* __restrict__ cls, const float* __restrict__ Wq,
                     const float* __restrict__ bq, float* __restrict__ q0,
                     float* __restrict__ h_full, float* __restrict__ svec,
                     float* __restrict__ scores) {
    const int d = blockIdx.x * 64 + threadIdx.x;   // 0..511
    float acc = 0.f;
    for (int in = 0; in < EMBED; ++in)
        acc = fmaf(cls[in], Wq[in * EMBED + d], acc);
    q0[d]     = acc + bq[d];
    h_full[d] = cls[d];
    svec[d]   = 0.f;
    #pragma unroll
    for (int i = 0; i < 16; ++i) scores[d * 16 + i] = 0.f;
}

// ============================================================
// 3) u[in] = Wk[in,:] . q0   (so scores = h . u)  grid 32 x 256
// ============================================================
__global__ void k_u(const float* __restrict__ Wk, const float* __restrict__ q0,
                    float* __restrict__ u) {
    const int wave = blockIdx.x * 4 + (threadIdx.x >> 6);  // 0..127
    const int lane = threadIdx.x & 63;
    const float4* q4 = (const float4*)q0;
    float4 qa = q4[lane * 2], qb = q4[lane * 2 + 1];
    for (int rr = 0; rr < 4; ++rr) {
        const int row = wave * 4 + rr;                     // 0..511
        const float4* wr = (const float4*)(Wk + (size_t)row * EMBED);
        float4 a = wr[lane * 2], b = wr[lane * 2 + 1];
        float acc = a.x*qa.x + a.y*qa.y + a.z*qa.z + a.w*qa.w
                  + b.x*qb.x + b.y*qb.y + b.z*qb.z + b.w*qb.w;
        for (int off = 32; off; off >>= 1) acc += __shfl_down(acc, off);
        if (lane == 0) u[row] = acc;
    }
}

// ============================================================
// 4) GEMM: h_full[1+a][n] = relu( x[a,:] @ w1t[n,:]^T + b1[n] )
//    + fused scores[1+a] = h_row . u  (raw dot, scaled later)
//    128x128 tile, BK=64, dbuf LDS (64KB), reg-staged, XOR-swizzled
//    grid 256 (64 M x 4 N), block 256 (4 waves 2x2)
// ============================================================
__global__ __launch_bounds__(256) void k_gemm(const float* __restrict__ x,
                                              const unsigned short* __restrict__ w1t,
                                              const float* __restrict__ b1,
                                              const float* __restrict__ u,
                                              float* __restrict__ h_full,
                                              float* __restrict__ scores) {
    __shared__ unsigned short As[2][128 * 64];   // 16 KB x2
    __shared__ unsigned short Bs[2][128 * 64];   // 16 KB x2
    const int tid  = threadIdx.x;
    const int wave = tid >> 6;
    const int lane = tid & 63;
    const int gm   = blockIdx.x >> 2;            // 0..63
    const int gn   = blockIdx.x & 3;             // 0..3
    const int wr   = wave >> 1, wc = wave & 1;
    const int fr   = lane & 15, fq = lane >> 4;

    // staging geometry: octet o = oi*256 + tid; row = o>>3 (0..127), k8 = o&7
    // A octet: 8 f32 (32B) from x ; B octet: 8 bf16 (16B) from w1t
    // LDS dst (both): shorts idx = row*64 + ((k8 ^ (row&7)))*8   [XOR swizzle]
    int dstoff[4];
    size_t srcA[4], srcB[4];
    #pragma unroll
    for (int oi = 0; oi < 4; ++oi) {
        const int o = oi * 256 + tid;
        const int row = o >> 3, k8 = o & 7;
        dstoff[oi] = row * 64 + (k8 ^ (row & 7)) * 8;
        const int xrow = min(gm * 128 + row, NPATCH - 1);      // clamp OOB row
        srcA[oi] = (size_t)xrow * INDIM + k8 * 8;
        srcB[oi] = (size_t)(gn * 128 + row) * INDIM + k8 * 8;
    }

    f32x4 acc[4][4] = {};
    float4 ar[4][2];     // staged A f32 (8 per octet)
    int4   br[4];        // staged B bf16 (8 per octet)

    // fragment read offsets (shorts): row*64 + ((kk*4+fq)^(row&7))*8
    int aoff[4], boff[4];
    #pragma unroll
    for (int mi = 0; mi < 4; ++mi) {
        const int row = wr * 64 + mi * 16 + fr;
        aoff[mi] = row * 64 + (((row & 7)) ^ fq) * 8;   // kk=0; kk=1 == xor 32 shorts
        const int col = wc * 64 + mi * 16 + fr;
        boff[mi] = col * 64 + (((col & 7)) ^ fq) * 8;
    }

#define LOADT(k0)  do { \
    _Pragma("unroll") \
    for (int oi = 0; oi < 4; ++oi) { \
        const float4* pa = (const float4*)(x + srcA[oi] + (k0)); \
        ar[oi][0] = pa[0]; ar[oi][1] = pa[1]; \
        br[oi] = *(const int4*)(w1t + srcB[oi] + (k0)); \
    } } while (0)

#define WRITET(buf) do { \
    _Pragma("unroll") \
    for (int oi = 0; oi < 4; ++oi) { \
        int4 aw; \
        aw.x = (int)cvtpk_bf16(ar[oi][0].x, ar[oi][0].y); \
        aw.y = (int)cvtpk_bf16(ar[oi][0].z, ar[oi][0].w); \
        aw.z = (int)cvtpk_bf16(ar[oi][1].x, ar[oi][1].y); \
        aw.w = (int)cvtpk_bf16(ar[oi][1].z, ar[oi][1].w); \
        *(int4*)&As[buf][dstoff[oi]] = aw; \
        *(int4*)&Bs[buf][dstoff[oi]] = br[oi]; \
    } } while (0)

    // prologue: tile 0
    LOADT(0);
    WRITET(0);
    __syncthreads();

    int cur = 0;
    for (int t = 0; t < 16; ++t) {
        if (t < 15) LOADT((t + 1) * 64);          // issue next-tile global loads early
        // compute tile t from buf[cur]
        #pragma unroll
        for (int kk = 0; kk < 2; ++kk) {
            bf16x8 af[4], bfr[4];
            #pragma unroll
            for (int mi = 0; mi < 4; ++mi)
                af[mi] = *(const bf16x8*)&As[cur][aoff[mi] ^ (kk * 32)];
            #pragma unroll
            for (int ni = 0; ni < 4; ++ni)
                bfr[ni] = *(const bf16x8*)&Bs[cur][boff[ni] ^ (kk * 32)];
            #pragma unroll
            for (int mi = 0; mi < 4; ++mi)
                #pragma unroll
                for (int ni = 0; ni < 4; ++ni)
                    acc[mi][ni] = __builtin_amdgcn_mfma_f32_16x16x32_bf16(af[mi], bfr[ni], acc[mi][ni], 0, 0, 0);
        }
        if (t < 15) WRITET(cur ^ 1);              // cvt + ds_write next tile
        __syncthreads();
        cur ^= 1;
    }

    // epilogue: row = gm*128 + wr*64 + mi*16 + fq*4 + r ; col = gn*128 + wc*64 + ni*16 + fr
    float uv[4], bvv[4];
    #pragma unroll
    for (int ni = 0; ni < 4; ++ni) {
        const int col = gn * 128 + wc * 64 + ni * 16 + fr;
        uv[ni] = u[col];
        bvv[ni] = b1[col];
    }
    #pragma unroll
    for (int mi = 0; mi < 4; ++mi) {
        #pragma unroll
        for (int r = 0; r < 4; ++r) {
            const int a = gm * 128 + wr * 64 + mi * 16 + fq * 4 + r;   // x row
            if (a < NPATCH) {
                float sc = 0.f;
                #pragma unroll
                for (int ni = 0; ni < 4; ++ni) {
                    const int col = gn * 128 + wc * 64 + ni * 16 + fr;
                    float v = fmaxf(acc[mi][ni][r] + bvv[ni], 0.f);
                    h_full[(size_t)(a + 1) * EMBED + col] = v;
                    sc = fmaf(v, uv[ni], sc);
                }
                // reduce over fr lanes (lane bits 0..3)
                sc += __shfl_xor(sc, 1);
                sc += __shfl_xor(sc, 2);
                sc += __shfl_xor(sc, 4);
                sc += __shfl_xor(sc, 8);
                if (fr == 0) atomicAdd(&scores[a + 1], sc);
            }
        }
    }
#undef LOADT
#undef WRITET
}

// ============================================================
// 5) chunk softmax (16 x 512) then full softmax -> wts[8192]
//    1 block x 1024 threads; wave == chunk. Also computes scores[0].
// ============================================================
__global__ void k_softmax(const float* __restrict__ scores, const float* __restrict__ h_full,
                          const float* __restrict__ u, float* __restrict__ wts) {
    __shared__ float redA[16], redB[16];
    __shared__ float s0sh;
    const int t = threadIdx.x, wv = t >> 6, lane = t & 63;
    const float rs = 0.04419417382415922f;   // 1/sqrt(512)

    if (wv == 0) {   // score for cls row (row 0 of h_full)
        const float4* hr = (const float4*)h_full;
        const float4* u4 = (const float4*)u;
        float4 a = hr[lane * 2], b = hr[lane * 2 + 1];
        float4 qa = u4[lane * 2], qb = u4[lane * 2 + 1];
        float acc = a.x*qa.x + a.y*qa.y + a.z*qa.z + a.w*qa.w
                  + b.x*qb.x + b.y*qb.y + b.z*qb.z + b.w*qb.w;
        for (int off = 32; off; off >>= 1) acc += __shfl_down(acc, off);
        if (lane == 0) s0sh = acc * rs;
    }
    __syncthreads();

    const float4* s4 = (const float4*)scores;
    float4 a = s4[2 * t], b = s4[2 * t + 1];
    float v[8] = {a.x*rs, a.y*rs, a.z*rs, a.w*rs, b.x*rs, b.y*rs, b.z*rs, b.w*rs};
    if (t == 0) v[0] = s0sh;

    // per-chunk softmax (one wave == one 512-chunk)
    float mx = v[0];
    #pragma unroll
    for (int j = 1; j < 8; ++j) mx = fmaxf(mx, v[j]);
    for (int off = 32; off; off >>= 1) mx = fmaxf(mx, __shfl_xor(mx, off));
    float sm = 0.f;
    #pragma unroll
    for (int j = 0; j < 8; ++j) { v[j] = expf(v[j] - mx); sm += v[j]; }
    for (int off = 32; off; off >>= 1) sm += __shfl_xor(sm, off);
    float inv = 1.f / sm;
    #pragma unroll
    for (int j = 0; j < 8; ++j) v[j] *= inv;

    // full softmax over all 8192
    float m2 = v[0];
    #pragma unroll
    for (int j = 1; j < 8; ++j) m2 = fmaxf(m2, v[j]);
    for (int off = 32; off; off >>= 1) m2 = fmaxf(m2, __shfl_xor(m2, off));
    if (lane == 0) redA[wv] = m2;
    __syncthreads();
    float gm = redA[0];
    for (int i = 1; i < 16; ++i) gm = fmaxf(gm, redA[i]);
    float s2 = 0.f;
    #pragma unroll
    for (int j = 0; j < 8; ++j) { v[j] = expf(v[j] - gm); s2 += v[j]; }
    for (int off = 32; off; off >>= 1) s2 += __shfl_xor(s2, off);
    if (lane == 0) redB[wv] = s2;
    __syncthreads();
    float gs = 0.f;
    for (int i = 0; i < 16; ++i) gs += redB[i];
    float gi = 1.f / gs;
    float4 o1 = {v[0] * gi, v[1] * gi, v[2] * gi, v[3] * gi};
    float4 o2 = {v[4] * gi, v[5] * gi, v[6] * gi, v[7] * gi};
    float4* w4 = (float4*)wts;
    w4[2 * t] = o1; w4[2 * t + 1] = o2;
}

// ============================================================
// 6) svec[d] = sum_j wts[j] * h_full[j][d]   grid 128 x 256
// ============================================================
__global__ void k_wsum(const float* __restrict__ h_full, const float* __restrict__ wts,
                       float* __restrict__ svec) {
    const int b = blockIdx.x, t = threadIdx.x;
    float a0 = 0.f, a1 = 0.f;
    const int j0 = b * 64;
    for (int j = j0; j < j0 + 64; ++j) {
        const float wj = wts[j];
        const float* hr = h_full + (size_t)j * EMBED;
        a0 = fmaf(wj, hr[t], a0);
        a1 = fmaf(wj, hr[t + 256], a1);
    }
    atomicAdd(&svec[t], a0);
    atomicAdd(&svec[t + 256], a1);
}

// ============================================================
// 7) attn0[d] = svec @ Wv + bv        grid 8 x 64
// ============================================================
__global__ void k_attn0(const float* __restrict__ svec, const float* __restrict__ Wv,
                        const float* __restrict__ bv, float* __restrict__ attn0) {
    const int d = blockIdx.x * 64 + threadIdx.x;
    float acc = 0.f;
    for (int e = 0; e < EMBED; ++e)
        acc = fmaf(svec[e], Wv[(size_t)e * EMBED + d], acc);
    attn0[d] = acc + bv[d];
}

// ============================================================
// 8) r0[d] = cls[d] + attn0 @ Wo + bo   grid 8 x 64
// ============================================================
__global__ void k_r0(const float* __restrict__ cls, const float* __restrict__ attn0,
                     const float* __restrict__ Wo, const float* __restrict__ bo,
                     float* __restrict__ r0) {
    const int d = blockIdx.x * 64 + threadIdx.x;
    float acc = 0.f;
    for (int e = 0; e < EMBED; ++e)
        acc = fmaf(attn0[e], Wo[(size_t)e * EMBED + d], acc);
    r0[d] = cls[d] + acc + bo[d];
}

// ============================================================
// 9) LayerNorm(r0) -> logits = hn @ Wc + bc    1 block x 512
// ============================================================
__global__ void k_final(const float* __restrict__ r0, const float* __restrict__ ln_g,
                        const float* __restrict__ ln_b, const float* __restrict__ Wc,
                        const float* __restrict__ bc, float* __restrict__ out) {
    __shared__ float red[8];
    const int t = threadIdx.x, wv = t >> 6, lane = t & 63;
    const float x = r0[t];

    float sm = x;
    for (int off = 32; off; off >>= 1) sm += __shfl_down(sm, off);
    if (lane == 0) red[wv] = sm;
    __syncthreads();
    float mu = 0.f;
    for (int i = 0; i < 8; ++i) mu += red[i];
    mu *= (1.f / 512.f);
    const float dx = x - mu;

    __syncthreads();
    float q = dx * dx;
    for (int off = 32; off; off >>= 1) q += __shfl_down(q, off);
    if (lane == 0) red[wv] = q;
    __syncthreads();
    float var = 0.f;
    for (int i = 0; i < 8; ++i) var += red[i];
    var *= (1.f / 512.f);

    const float hn = dx / sqrtf(var + 1e-5f) * ln_g[t] + ln_b[t];
    float p0 = hn * Wc[2 * t];
    float p1 = hn * Wc[2 * t + 1];

    __syncthreads();
    for (int off = 32; off; off >>= 1) p0 += __shfl_down(p0, off);
    if (lane == 0) red[wv] = p0;
    __syncthreads();
    if (t == 0) {
        float tot = 0.f;
        for (int i = 0; i < 8; ++i) tot += red[i];
        out[0] = tot + bc[0];
    }
    __syncthreads();
    for (int off = 32; off; off >>= 1) p1 += __shfl_down(p1, off);
    if (lane == 0) red[wv] = p1;
    __syncthreads();
    if (t == 0) {
        float tot = 0.f;
        for (int i = 0; i < 8; ++i) tot += red[i];
        out[1] = tot + bc[1];
    }
}

// ============================================================
extern "C" void kernel_launch(void* const* d_in, const int* in_sizes, int n_in,
                              void* d_out, int out_size, void* d_ws, size_t ws_size,
                              hipStream_t stream) {
    const float* x    = (const float*)d_in[0];
    const float* W1   = (const float*)d_in[1];
    const float* b1   = (const float*)d_in[2];
    const float* cls  = (const float*)d_in[3];
    const float* Wq   = (const float*)d_in[4];
    const float* bq   = (const float*)d_in[5];
    const float* Wk   = (const float*)d_in[6];
    const float* bk   = (const float*)d_in[7];   (void)bk;  // uniform shift cancels in softmax
    const float* Wv   = (const float*)d_in[8];
    const float* bv   = (const float*)d_in[9];
    const float* Wo   = (const float*)d_in[10];
    const float* bo   = (const float*)d_in[11];
    const float* ln_g = (const float*)d_in[12];
    const float* ln_b = (const float*)d_in[13];
    const float* Wc   = (const float*)d_in[14];
    const float* bc   = (const float*)d_in[15];
    float* out = (float*)d_out;

    char* ws = (char*)d_ws;
    unsigned short* w1t    = (unsigned short*)(ws);                    // 1 MB
    float*          h_full = (float*)(ws + 1048576);                   // 16 MB
    float*          scores = (float*)(ws + 17825792);                  // 32 KB
    float*          wts    = (float*)(ws + 17858560);                  // 32 KB
    float*          q0     = (float*)(ws + 17891328);
    float*          u      = (float*)(ws + 17893376);
    float*          svec   = (float*)(ws + 17895424);
    float*          attn0  = (float*)(ws + 17897472);
    float*          r0     = (float*)(ws + 17899520);

    k_transpose_w1<<<512, 256, 0, stream>>>(W1, w1t);
    k_q0         <<<8,    64, 0, stream>>>(cls, Wq, bq, q0, h_full, svec, scores);
    k_u          <<<32,  256, 0, stream>>>(Wk, q0, u);
    k_gemm       <<<256, 256, 0, stream>>>(x, w1t, b1, u, h_full, scores);
    k_softmax    <<<1,  1024, 0, stream>>>(scores, h_full, u, wts);
    k_wsum       <<<128, 256, 0, stream>>>(h_full, wts, svec);
    k_attn0      <<<8,    64, 0, stream>>>(svec, Wv, bv, attn0);
    k_r0         <<<8,    64, 0, stream>>>(cls, attn0, Wo, bo, r0);
    k_final      <<<1,   512, 0, stream>>>(r0, ln_g, ln_b, Wc, bc, out);
}

// Round 4
// 174.954 us; speedup vs baseline: 1.1919x; 1.1756x over previous
//
#include <hip/hip_runtime.h>
#include <math.h>

// ---------- types ----------
typedef __attribute__((ext_vector_type(8))) short bf16x8;   // 8 x bf16
typedef __attribute__((ext_vector_type(4))) float f32x4;

#define AS1(p) ((__attribute__((address_space(1))) void*)(uintptr_t)(p))
#define AS3(p) ((__attribute__((address_space(3))) void*)(p))

static __device__ __forceinline__ unsigned short f2bf(float f) {
    unsigned int u = __float_as_uint(f);
    unsigned int r = (u + 0x7fffu + ((u >> 16) & 1u)) >> 16;   // RNE
    return (unsigned short)r;
}
static __device__ __forceinline__ unsigned int cvtpk_bf16(float lo, float hi) {
    unsigned int r;
    asm("v_cvt_pk_bf16_f32 %0, %1, %2" : "=v"(r) : "v"(lo), "v"(hi));
    return r;
}

// ---------- sizes ----------
#define NPATCH 8191
#define NTOK   8192          // with cls row 0
#define INDIM  1024
#define EMBED  512

// ============================================================
// 1) k_pre: blocks 0..511  -> W1 transpose to w1t [N][K] bf16
//           blocks 512..515 -> q0 = cls@Wq+bq ; inits
// ============================================================
__global__ void k_pre(const float* __restrict__ W1, unsigned short* __restrict__ w1t,
                      const float* __restrict__ cls, const float* __restrict__ Wq,
                      const float* __restrict__ bq, const float* __restrict__ bv,
                      const float* __restrict__ bo,
                      float* __restrict__ q0, float* __restrict__ h_full,
                      float* __restrict__ svec, float* __restrict__ attn0,
                      float* __restrict__ r0, float* __restrict__ scores) {
    const int b = blockIdx.x;
    const int t = threadIdx.x;
    if (b < 512) {
        __shared__ float tile[32][33];
        const int bk = b >> 4;               // 0..31 (K tiles)
        const int bn = b & 15;               // 0..15 (N tiles)
        const int r  = t >> 3;               // 0..31
        const int c4 = (t & 7) * 4;          // 0,4,..,28
        float4 v = *(const float4*)(W1 + (size_t)(bk * 32 + r) * EMBED + bn * 32 + c4);
        tile[r][c4 + 0] = v.x; tile[r][c4 + 1] = v.y; tile[r][c4 + 2] = v.z; tile[r][c4 + 3] = v.w;
        __syncthreads();
        ushort4 o;
        o.x = f2bf(tile[c4 + 0][r]); o.y = f2bf(tile[c4 + 1][r]);
        o.z = f2bf(tile[c4 + 2][r]); o.w = f2bf(tile[c4 + 3][r]);
        *(ushort4*)(w1t + (size_t)(bn * 32 + r) * INDIM + bk * 32 + c4) = o;
    } else if (t < 128) {
        const int d = (b - 512) * 128 + t;   // 0..511
        float acc = 0.f;
        for (int in = 0; in < EMBED; ++in)
            acc = fmaf(cls[in], Wq[in * EMBED + d], acc);
        q0[d]     = acc + bq[d];
        h_full[d] = cls[d];
        svec[d]   = 0.f;
        attn0[d]  = bv[d];                   // bias pre-seeded for atomic accumulation
        r0[d]     = cls[d] + bo[d];          // residual + bias pre-seeded
        #pragma unroll
        for (int i = 0; i < 16; ++i) scores[d * 16 + i] = 0.f;
    }
}

// ============================================================
// 2) u[in] = Wk[in,:] . q0   (so scores = h . u)  grid 32 x 256
// ============================================================
__global__ void k_u(const float* __restrict__ Wk, const float* __restrict__ q0,
                    float* __restrict__ u) {
    const int wave = blockIdx.x * 4 + (threadIdx.x >> 6);  // 0..127
    const int lane = threadIdx.x & 63;
    const float4* q4 = (const float4*)q0;
    float4 qa = q4[lane * 2], qb = q4[lane * 2 + 1];
    for (int rr = 0; rr < 4; ++rr) {
        const int row = wave * 4 + rr;                     // 0..511
        const float4* wr = (const float4*)(Wk + (size_t)row * EMBED);
        float4 a = wr[lane * 2], b = wr[lane * 2 + 1];
        float acc = a.x*qa.x + a.y*qa.y + a.z*qa.z + a.w*qa.w
                  + b.x*qb.x + b.y*qb.y + b.z*qb.z + b.w*qb.w;
        for (int off = 32; off; off >>= 1) acc += __shfl_down(acc, off);
        if (lane == 0) u[row] = acc;
    }
}

// ============================================================
// 3) GEMM: h_full[1+a][n] = relu( x[a,:] @ w1t[n,:]^T + b1[n] )
//    + fused scores[1+a] = h_row . u  (raw dot, scaled in softmax)
//    64x64 tile, BK=64, dbuf LDS (32KB), grid 1024 (4 blk/CU), 256 thr
//    A: reg-staged f32->bf16 cvt, XOR-swizzled ds_write
//    B: global_load_lds with pre-swizzled GLOBAL source (rule #21)
//    XCD-chunked tile map: all 8 gn-siblings of a gm on one XCD
// ============================================================
__global__ __launch_bounds__(256) void k_gemm(const float* __restrict__ x,
                                              const unsigned short* __restrict__ w1t,
                                              const float* __restrict__ b1,
                                              const float* __restrict__ u,
                                              float* __restrict__ h_full,
                                              float* __restrict__ scores) {
    __shared__ unsigned short As[2][64 * 64];    // 8 KB x2
    __shared__ unsigned short Bs[2][64 * 64];    // 8 KB x2
    const int tid  = threadIdx.x;
    const int wave = tid >> 6;
    const int lane = tid & 63;
    const int bid  = blockIdx.x;
    const int tile = ((bid & 7) << 7) | (bid >> 3);   // XCD-chunked, bijective (1024 % 8 == 0)
    const int gm   = tile >> 3;                  // 0..127
    const int gn   = tile & 7;                   // 0..7
    const int wr   = wave >> 1, wc = wave & 1;
    const int fr   = lane & 15, fq = lane >> 4;

    // ---- A staging: 2 octets/thread. octet o = oi*256+tid: row = o>>3, slot = o&7
    int dstA[2];
    size_t srcA[2];
    #pragma unroll
    for (int oi = 0; oi < 2; ++oi) {
        const int row = oi * 32 + (tid >> 3), slot = tid & 7;
        dstA[oi] = row * 64 + (slot ^ (row & 7)) * 8;
        const int xrow = min(gm * 64 + row, NPATCH - 1);   // clamp OOB row
        srcA[oi] = (size_t)xrow * INDIM + slot * 8;
    }
    // ---- B staging: 2 global_load_lds per wave (8 rows each, 1KB)
    //      global source pre-swizzled so linear LDS == swizzled layout
    size_t srcB[2];
    int ldsB[2];
    #pragma unroll
    for (int i = 0; i < 2; ++i) {
        const int rbase = wave * 16 + i * 8;
        const int r = rbase + (lane >> 3), s = lane & 7;
        srcB[i] = (size_t)(gn * 64 + r) * INDIM + (s ^ (r & 7)) * 8;
        ldsB[i] = rbase * 64;
    }

    f32x4 acc[2][2] = {};
    float4 ar[2][2];

    // fragment read offsets (shorts), kk=0; kk=1 == ^32
    int aoff[2], boff[2];
    #pragma unroll
    for (int mi = 0; mi < 2; ++mi) {
        const int row = wr * 32 + mi * 16 + fr;
        aoff[mi] = row * 64 + ((row & 7) ^ fq) * 8;
        const int col = wc * 32 + mi * 16 + fr;
        boff[mi] = col * 64 + ((col & 7) ^ fq) * 8;
    }

#define LOADB(buf, k0) do { \
    _Pragma("unroll") \
    for (int i = 0; i < 2; ++i) \
        __builtin_amdgcn_global_load_lds(AS1(w1t + srcB[i] + (k0)), \
                                         AS3(&Bs[buf][ldsB[i]]), 16, 0, 0); \
    } while (0)

#define LOADA(k0) do { \
    _Pragma("unroll") \
    for (int oi = 0; oi < 2; ++oi) { \
        const float4* pa = (const float4*)(x + srcA[oi] + (k0)); \
        ar[oi][0] = pa[0]; ar[oi][1] = pa[1]; \
    } } while (0)

#define WRITEA(buf) do { \
    _Pragma("unroll") \
    for (int oi = 0; oi < 2; ++oi) { \
        int4 aw; \
        aw.x = (int)cvtpk_bf16(ar[oi][0].x, ar[oi][0].y); \
        aw.y = (int)cvtpk_bf16(ar[oi][0].z, ar[oi][0].w); \
        aw.z = (int)cvtpk_bf16(ar[oi][1].x, ar[oi][1].y); \
        aw.w = (int)cvtpk_bf16(ar[oi][1].z, ar[oi][1].w); \
        *(int4*)&As[buf][dstA[oi]] = aw; \
    } } while (0)

    // prologue: tile 0
    LOADB(0, 0);
    LOADA(0);
    WRITEA(0);
    __syncthreads();

    int cur = 0;
    for (int t = 0; t < 16; ++t) {
        if (t < 15) {
            LOADB(cur ^ 1, (t + 1) * 64);     // async B prefetch into other buffer
            LOADA((t + 1) * 64);              // A f32 loads issued early
        }
        #pragma unroll
        for (int kk = 0; kk < 2; ++kk) {
            bf16x8 af[2], bfr[2];
            #pragma unroll
            for (int mi = 0; mi < 2; ++mi)
                af[mi] = *(const bf16x8*)&As[cur][aoff[mi] ^ (kk * 32)];
            #pragma unroll
            for (int ni = 0; ni < 2; ++ni)
                bfr[ni] = *(const bf16x8*)&Bs[cur][boff[ni] ^ (kk * 32)];
            #pragma unroll
            for (int mi = 0; mi < 2; ++mi)
                #pragma unroll
                for (int ni = 0; ni < 2; ++ni)
                    acc[mi][ni] = __builtin_amdgcn_mfma_f32_16x16x32_bf16(af[mi], bfr[ni], acc[mi][ni], 0, 0, 0);
        }
        if (t < 15) WRITEA(cur ^ 1);          // cvt + ds_write (waits A loads via reg dep)
        __syncthreads();                      // drains gload_lds + ds_writes
        cur ^= 1;
    }

    // epilogue: a = gm*64 + wr*32 + mi*16 + fq*4 + rr ; col = gn*64 + wc*32 + ni*16 + fr
    float uv[2], bvv[2];
    #pragma unroll
    for (int ni = 0; ni < 2; ++ni) {
        const int col = gn * 64 + wc * 32 + ni * 16 + fr;
        uv[ni]  = u[col];
        bvv[ni] = b1[col];
    }
    #pragma unroll
    for (int mi = 0; mi < 2; ++mi) {
        #pragma unroll
        for (int rr = 0; rr < 4; ++rr) {
            const int a = gm * 64 + wr * 32 + mi * 16 + fq * 4 + rr;
            if (a < NPATCH) {
                float sc = 0.f;
                #pragma unroll
                for (int ni = 0; ni < 2; ++ni) {
                    const int col = gn * 64 + wc * 32 + ni * 16 + fr;
                    float v = fmaxf(acc[mi][ni][rr] + bvv[ni], 0.f);
                    h_full[(size_t)(a + 1) * EMBED + col] = v;
                    sc = fmaf(v, uv[ni], sc);
                }
                sc += __shfl_xor(sc, 1);
                sc += __shfl_xor(sc, 2);
                sc += __shfl_xor(sc, 4);
                sc += __shfl_xor(sc, 8);
                if (fr == 0) atomicAdd(&scores[a + 1], sc);
            }
        }
    }
#undef LOADB
#undef LOADA
#undef WRITEA
}

// ============================================================
// 4) chunk softmax (16 x 512) then full softmax -> wts[8192]
//    1 block x 1024 threads; wave == chunk. Also computes scores[0].
// ============================================================
__global__ void k_softmax(const float* __restrict__ scores, const float* __restrict__ h_full,
                          const float* __restrict__ u, float* __restrict__ wts) {
    __shared__ float redA[16], redB[16];
    __shared__ float s0sh;
    const int t = threadIdx.x, wv = t >> 6, lane = t & 63;
    const float rs = 0.04419417382415922f;   // 1/sqrt(512)

    if (wv == 0) {   // score for cls row (row 0 of h_full)
        const float4* hr = (const float4*)h_full;
        const float4* u4 = (const float4*)u;
        float4 a = hr[lane * 2], b = hr[lane * 2 + 1];
        float4 qa = u4[lane * 2], qb = u4[lane * 2 + 1];
        float acc = a.x*qa.x + a.y*qa.y + a.z*qa.z + a.w*qa.w
                  + b.x*qb.x + b.y*qb.y + b.z*qb.z + b.w*qb.w;
        for (int off = 32; off; off >>= 1) acc += __shfl_down(acc, off);
        if (lane == 0) s0sh = acc * rs;
    }
    __syncthreads();

    const float4* s4 = (const float4*)scores;
    float4 a = s4[2 * t], b = s4[2 * t + 1];
    float v[8] = {a.x*rs, a.y*rs, a.z*rs, a.w*rs, b.x*rs, b.y*rs, b.z*rs, b.w*rs};
    if (t == 0) v[0] = s0sh;

    // per-chunk softmax (one wave == one 512-chunk)
    float mx = v[0];
    #pragma unroll
    for (int j = 1; j < 8; ++j) mx = fmaxf(mx, v[j]);
    for (int off = 32; off; off >>= 1) mx = fmaxf(mx, __shfl_xor(mx, off));
    float sm = 0.f;
    #pragma unroll
    for (int j = 0; j < 8; ++j) { v[j] = expf(v[j] - mx); sm += v[j]; }
    for (int off = 32; off; off >>= 1) sm += __shfl_xor(sm, off);
    float inv = 1.f / sm;
    #pragma unroll
    for (int j = 0; j < 8; ++j) v[j] *= inv;

    // full softmax over all 8192
    float m2 = v[0];
    #pragma unroll
    for (int j = 1; j < 8; ++j) m2 = fmaxf(m2, v[j]);
    for (int off = 32; off; off >>= 1) m2 = fmaxf(m2, __shfl_xor(m2, off));
    if (lane == 0) redA[wv] = m2;
    __syncthreads();
    float gm = redA[0];
    for (int i = 1; i < 16; ++i) gm = fmaxf(gm, redA[i]);
    float s2 = 0.f;
    #pragma unroll
    for (int j = 0; j < 8; ++j) { v[j] = expf(v[j] - gm); s2 += v[j]; }
    for (int off = 32; off; off >>= 1) s2 += __shfl_xor(s2, off);
    if (lane == 0) redB[wv] = s2;
    __syncthreads();
    float gs = 0.f;
    for (int i = 0; i < 16; ++i) gs += redB[i];
    float gi = 1.f / gs;
    float4 o1 = {v[0] * gi, v[1] * gi, v[2] * gi, v[3] * gi};
    float4 o2 = {v[4] * gi, v[5] * gi, v[6] * gi, v[7] * gi};
    float4* w4 = (float4*)wts;
    w4[2 * t] = o1; w4[2 * t + 1] = o2;
}

// ============================================================
// 5) svec[d] = sum_j wts[j] * h_full[j][d]   grid 256 x 256
// ============================================================
__global__ void k_wsum(const float* __restrict__ h_full, const float* __restrict__ wts,
                       float* __restrict__ svec) {
    const int b = blockIdx.x, t = threadIdx.x;
    float a0 = 0.f, a1 = 0.f;
    const int j0 = b * 32;
    for (int j = j0; j < j0 + 32; ++j) {
        const float wj = wts[j];
        const float* hr = h_full + (size_t)j * EMBED;
        a0 = fmaf(wj, hr[t], a0);
        a1 = fmaf(wj, hr[t + 256], a1);
    }
    atomicAdd(&svec[t], a0);
    atomicAdd(&svec[t + 256], a1);
}

// ============================================================
// 6) attn0 += svec @ Wv  (attn0 pre-seeded with bv)  grid 32 x 256
// ============================================================
__global__ void k_attn0(const float* __restrict__ svec, const float* __restrict__ Wv,
                        float* __restrict__ attn0) {
    const int b = blockIdx.x, t = threadIdx.x;
    float a0 = 0.f, a1 = 0.f;
    const int e0 = b * 16;
    for (int e = e0; e < e0 + 16; ++e) {
        const float s = svec[e];
        const float* wr = Wv + (size_t)e * EMBED;
        a0 = fmaf(s, wr[t], a0);
        a1 = fmaf(s, wr[t + 256], a1);
    }
    atomicAdd(&attn0[t], a0);
    atomicAdd(&attn0[t + 256], a1);
}

// ============================================================
// 7) r0 += attn0 @ Wo  (r0 pre-seeded with cls+bo)  grid 32 x 256
// ============================================================
__global__ void k_r0(const float* __restrict__ attn0, const float* __restrict__ Wo,
                     float* __restrict__ r0) {
    const int b = blockIdx.x, t = threadIdx.x;
    float a0 = 0.f, a1 = 0.f;
    const int e0 = b * 16;
    for (int e = e0; e < e0 + 16; ++e) {
        const float s = attn0[e];
        const float* wr = Wo + (size_t)e * EMBED;
        a0 = fmaf(s, wr[t], a0);
        a1 = fmaf(s, wr[t + 256], a1);
    }
    atomicAdd(&r0[t], a0);
    atomicAdd(&r0[t + 256], a1);
}

// ============================================================
// 8) LayerNorm(r0) -> logits = hn @ Wc + bc    1 block x 512
// ============================================================
__global__ void k_final(const float* __restrict__ r0, const float* __restrict__ ln_g,
                        const float* __restrict__ ln_b, const float* __restrict__ Wc,
                        const float* __restrict__ bc, float* __restrict__ out) {
    __shared__ float red[8];
    const int t = threadIdx.x, wv = t >> 6, lane = t & 63;
    const float x = r0[t];

    float sm = x;
    for (int off = 32; off; off >>= 1) sm += __shfl_down(sm, off);
    if (lane == 0) red[wv] = sm;
    __syncthreads();
    float mu = 0.f;
    for (int i = 0; i < 8; ++i) mu += red[i];
    mu *= (1.f / 512.f);
    const float dx = x - mu;

    __syncthreads();
    float q = dx * dx;
    for (int off = 32; off; off >>= 1) q += __shfl_down(q, off);
    if (lane == 0) red[wv] = q;
    __syncthreads();
    float var = 0.f;
    for (int i = 0; i < 8; ++i) var += red[i];
    var *= (1.f / 512.f);

    const float hn = dx / sqrtf(var + 1e-5f) * ln_g[t] + ln_b[t];
    float p0 = hn * Wc[2 * t];
    float p1 = hn * Wc[2 * t + 1];

    __syncthreads();
    for (int off = 32; off; off >>= 1) p0 += __shfl_down(p0, off);
    if (lane == 0) red[wv] = p0;
    __syncthreads();
    if (t == 0) {
        float tot = 0.f;
        for (int i = 0; i < 8; ++i) tot += red[i];
        out[0] = tot + bc[0];
    }
    __syncthreads();
    for (int off = 32; off; off >>= 1) p1 += __shfl_down(p1, off);
    if (lane == 0) red[wv] = p1;
    __syncthreads();
    if (t == 0) {
        float tot = 0.f;
        for (int i = 0; i < 8; ++i) tot += red[i];
        out[1] = tot + bc[1];
    }
}

// ============================================================
extern "C" void kernel_launch(void* const* d_in, const int* in_sizes, int n_in,
                              void* d_out, int out_size, void* d_ws, size_t ws_size,
                              hipStream_t stream) {
    const float* x    = (const float*)d_in[0];
    const float* W1   = (const float*)d_in[1];
    const float* b1   = (const float*)d_in[2];
    const float* cls  = (const float*)d_in[3];
    const float* Wq   = (const float*)d_in[4];
    const float* bq   = (const float*)d_in[5];
    const float* Wk   = (const float*)d_in[6];
    const float* bk   = (const float*)d_in[7];   (void)bk;  // uniform shift cancels in softmax
    const float* Wv   = (const float*)d_in[8];
    const float* bv   = (const float*)d_in[9];
    const float* Wo   = (const float*)d_in[10];
    const float* bo   = (const float*)d_in[11];
    const float* ln_g = (const float*)d_in[12];
    const float* ln_b = (const float*)d_in[13];
    const float* Wc   = (const float*)d_in[14];
    const float* bc   = (const float*)d_in[15];
    float* out = (float*)d_out;

    char* ws = (char*)d_ws;
    unsigned short* w1t    = (unsigned short*)(ws);                    // 1 MB
    float*          h_full = (float*)(ws + 1048576);                   // 16 MB
    float*          scores = (float*)(ws + 17825792);                  // 32 KB
    float*          wts    = (float*)(ws + 17858560);                  // 32 KB
    float*          q0     = (float*)(ws + 17891328);
    float*          u      = (float*)(ws + 17893376);
    float*          svec   = (float*)(ws + 17895424);
    float*          attn0  = (float*)(ws + 17897472);
    float*          r0     = (float*)(ws + 17899520);

    k_pre     <<<516, 256, 0, stream>>>(W1, w1t, cls, Wq, bq, bv, bo,
                                        q0, h_full, svec, attn0, r0, scores);
    k_u       <<<32,  256, 0, stream>>>(Wk, q0, u);
    k_gemm    <<<1024,256, 0, stream>>>(x, w1t, b1, u, h_full, scores);
    k_softmax <<<1,  1024, 0, stream>>>(scores, h_full, u, wts);
    k_wsum    <<<256, 256, 0, stream>>>(h_full, wts, svec);
    k_attn0   <<<32,  256, 0, stream>>>(svec, Wv, attn0);
    k_r0      <<<32,  256, 0, stream>>>(attn0, Wo, r0);
    k_final   <<<1,   512, 0, stream>>>(r0, ln_g, ln_b, Wc, bc, out);
}